// Round 14
// baseline (740.553 us; speedup 1.0000x reference)
//
#include <hip/hip_runtime.h>
#include <hip/hip_bf16.h>
#include <math.h>

using bf16 = __hip_bfloat16;
typedef __attribute__((ext_vector_type(8))) short short8;
typedef __attribute__((ext_vector_type(4))) float f32x4;

__device__ __forceinline__ float tof(float x) { return x; }
__device__ __forceinline__ float tof(bf16 x) { return __bfloat162float(x); }
__device__ __forceinline__ float b2f(unsigned short u) {
  union { float f; unsigned int i; } c; c.i = ((unsigned int)u) << 16; return c.f;
}
__device__ __forceinline__ unsigned short f2bu(float v) {
  bf16 h = __float2bfloat16(v);
  return *(unsigned short*)&h;
}
__device__ __forceinline__ void sto1(float* p, float v) { *p = v; }
__device__ __forceinline__ void sto1(bf16* p, float v) { *p = __float2bfloat16(v); }

__device__ __forceinline__ float gelu_exact(float x) {
  return 0.5f * x * (1.f + erff(x * 0.70710678118654752f));
}

// async global->LDS, 16B/lane; LDS dest = wave base + lane*16 (m97 pattern).
__device__ __forceinline__ void llds16(const bf16* g, short* l) {
  __builtin_amdgcn_global_load_lds((const __attribute__((address_space(1))) void*)g,
                                   (__attribute__((address_space(3))) void*)l, 16, 0, 0);
}

// ---------------------------------------------------------------------------
// Split-3 convention (fp32-faithful bf16 GEMM via K-extension) retained ONLY
// for proj (hconv3) and classifier (sbuf3). qkv/ff1/ff2 single-bf16 (floor
// 2^-7 constant across all de-splits, R1-R13).
// ---------------------------------------------------------------------------

// wqkv1[l][n(768)][k(256)] = bf16(w[l][k][n & 255]), single-bf16.
__global__ __launch_bounds__(256) void pack_qkv1_kernel(
    const float* __restrict__ wq, const float* __restrict__ wk,
    const float* __restrict__ wv, bf16* __restrict__ out)
{
  int idx = blockIdx.x * 256 + threadIdx.x;   // < 4*768*256
  int k = idx & 255;
  int nl = idx >> 8;
  int n = nl % 768, l = nl / 768;
  const float* src = (n < 256) ? wq : (n < 512 ? wk : wv);
  out[(long)l * 196608 + (long)n * 256 + k] =
      __float2bfloat16(src[(long)l * 65536 + k * 256 + (n & 255)]);
}

__global__ __launch_bounds__(256) void pack_qkvbias_kernel(
    const float* __restrict__ bq, const float* __restrict__ bk,
    const float* __restrict__ bv, float* __restrict__ out)
{
  int i = blockIdx.x * 256 + threadIdx.x;   // < 3072
  if (i >= 3072) return;
  int n = i % 768, l = i / 768;
  const float* src = (n < 256) ? bq : (n < 512 ? bk : bv);
  out[i] = src[l * 256 + (n & 255)];
}

// out[l][n][k] = in[l][k][n], bf16 (single)
__global__ __launch_bounds__(256) void tconv_kernel(
    const float* __restrict__ in, bf16* __restrict__ out,
    int K, int N, long sin, long sout)
{
  int l = blockIdx.z;
  int idx = blockIdx.x * 256 + threadIdx.x;
  int k = idx % K, n = idx / K;
  out[l * sout + idx] = __float2bfloat16(in[l * sin + (long)k * N + n]);
}

// out[l][n][3K] = B3-split of in[l][k][n]
__global__ __launch_bounds__(256) void tconv3_kernel(
    const float* __restrict__ in, bf16* __restrict__ out,
    int K, int N, long sin, long sout)
{
  int l = blockIdx.z;
  int idx = blockIdx.x * 256 + threadIdx.x;
  int k = idx % K, n = idx / K;
  float v = in[l * sin + (long)k * N + n];
  unsigned short hi = f2bu(v);
  unsigned short lo = f2bu(v - b2f(hi));
  unsigned short* o = (unsigned short*)out + l * sout + (long)n * (3 * K);
  o[k] = hi; o[K + k] = hi; o[2 * K + k] = lo;
}

__global__ __launch_bounds__(256) void f2b_kernel(
    const float* __restrict__ in, bf16* __restrict__ out, int n)
{
  int i = blockIdx.x * 256 + threadIdx.x;
  if (i < n) out[i] = __float2bfloat16(in[i]);
}

__global__ __launch_bounds__(256) void zero4_kernel(float* __restrict__ p) {
  int i = (blockIdx.x * 256 + threadIdx.x) * 4;
  float4 z; z.x = 0.f; z.y = 0.f; z.z = 0.f; z.w = 0.f;
  *(float4*)&p[i] = z;
}

// s = x1 + x2 -> A3 split (classifier input), one row per block
__global__ __launch_bounds__(256) void sumb3_kernel(
    const float* __restrict__ a, const float* __restrict__ b, bf16* __restrict__ o)
{
  int row = blockIdx.x, c = threadIdx.x;
  long i = (long)row * 256 + c;
  float v = a[i] + b[i];
  unsigned short hi = f2bu(v);
  unsigned short lo = f2bu(v - b2f(hi));
  unsigned short* op = (unsigned short*)o + (long)row * 768 + c;
  op[0] = hi; op[256] = lo; op[512] = hi;
}

// ---------------------------------------------------------------------------
// Conv frontend stage 1: conv0+dw1+pw1+bn1+relu -> A1[b][t][f][ci] bf16
// ---------------------------------------------------------------------------
__global__ __launch_bounds__(256) void front1_kernel(
    const float* __restrict__ x, const float* __restrict__ c0w,
    const float* __restrict__ d1w, const float* __restrict__ d1b,
    const float* __restrict__ p1w, const float* __restrict__ p1b,
    const float* __restrict__ g1, const float* __restrict__ b1,
    const float* __restrict__ m1, const float* __restrict__ v1,
    bf16* __restrict__ A1)
{
  __shared__ float sd[256];
  __shared__ float ss[128], st[128], sb[128];
  int tid = threadIdx.x;
  int bt = ((blockIdx.x & 7) << 9) | (blockIdx.x >> 3);   // XCD swizzle
  int b = bt >> 11, t = bt & 2047;
  if (tid < 128) {
    float s = g1[tid] * rsqrtf(v1[tid] + 1e-5f);
    ss[tid] = s;
    st[tid] = b1[tid] - m1[tid] * s;
    sb[tid] = p1b[tid];
  }
  {
    int c = tid >> 6, f = tid & 63;
    float cw = c0w[c];
    float acc = d1b[c];
#pragma unroll
    for (int kh = 0; kh < 3; ++kh) {
      int fi = f + kh - 1;
      if (fi < 0 || fi >= 64) continue;
#pragma unroll
      for (int kw = 0; kw < 3; ++kw) {
        int ti = t + kw - 1;
        if (ti < 0 || ti >= 2048) continue;
        acc += d1w[c * 9 + kh * 3 + kw] * cw * x[((long)b * 2048 + ti) * 64 + fi];
      }
    }
    sd[c * 64 + f] = acc;
  }
  int ci0 = (tid * 8) & 127;
  float wreg[8][4];
#pragma unroll
  for (int j = 0; j < 8; ++j) {
    f32x4 w4 = *(const f32x4*)&p1w[(ci0 + j) * 4];
#pragma unroll
    for (int c = 0; c < 4; ++c) wreg[j][c] = w4[c];
  }
  __syncthreads();
  float ssr[8], str[8], sbr[8];
#pragma unroll
  for (int j = 0; j < 8; ++j) {
    ssr[j] = ss[ci0 + j]; str[j] = st[ci0 + j]; sbr[j] = sb[ci0 + j];
  }
  long ob = (long)bt * 8192;
  unsigned short* A1u = (unsigned short*)A1;
#pragma unroll
  for (int it = 0; it < 4; ++it) {
    int f = it * 16 + (tid >> 4);
    float sdv[4];
#pragma unroll
    for (int c = 0; c < 4; ++c) sdv[c] = sd[c * 64 + f];
    short8 pkt;
#pragma unroll
    for (int j = 0; j < 8; ++j) {
      float pre = sbr[j];
#pragma unroll
      for (int c = 0; c < 4; ++c) pre = fmaf(wreg[j][c], sdv[c], pre);
      pkt[j] = (short)f2bu(fmaxf(fmaf(ssr[j], pre, str[j]), 0.f));
    }
    *(short8*)&A1u[ob + it * 2048 + tid * 8] = pkt;
  }
}

// ---------------------------------------------------------------------------
// Conv tail (measured-best design, ~96us): dw2 (VALU) -> dw2s LDS; pw2 (MFMA)
// with Bs-staged weights; bn2+relu+mean(f) -> hconv3 A3 split. XCD swizzle.
// ---------------------------------------------------------------------------
__global__ __launch_bounds__(256, 4) void convtail_kernel(
    const bf16* __restrict__ A1, const float* __restrict__ w,
    const float* __restrict__ wb, const bf16* __restrict__ w2b,
    const float* __restrict__ pb, const float* __restrict__ g2,
    const float* __restrict__ b2, const float* __restrict__ m2,
    const float* __restrict__ v2, bf16* __restrict__ hconv3)
{
  __shared__ short dw2s[64 * 136];
  __shared__ short Bs[64 * 136];
  __shared__ float red[1024];
  __shared__ float ssc[64], ssh[64];
  int tid = threadIdx.x;
  int lane = tid & 63, wv = tid >> 6;
  int quad = lane >> 4, l15 = lane & 15;
  int rw = (wv >> 1) * 32, cw = (wv & 1) * 32;
  int bt = ((blockIdx.x & 7) << 9) | (blockIdx.x >> 3);   // XCD swizzle
  int b = bt >> 11, t = bt & 2047;
  int ci8 = (tid & 15) * 8;
  float wreg[9][8], breg[8];
#pragma unroll
  for (int c = 0; c < 8; ++c) {
    breg[c] = wb[ci8 + c];
#pragma unroll
    for (int kk = 0; kk < 9; ++kk) wreg[kk][c] = w[(ci8 + c) * 9 + kk];
  }
  const unsigned short* A1u = (const unsigned short*)A1;
  for (int pass = 0; pass < 4; ++pass) {
    int f = pass * 16 + (tid >> 4);
    float a[8];
#pragma unroll
    for (int c = 0; c < 8; ++c) a[c] = breg[c];
#pragma unroll
    for (int kh = 0; kh < 3; ++kh) {
      int fi = f + kh - 1;
      if (fi < 0 || fi >= 64) continue;
#pragma unroll
      for (int kw = 0; kw < 3; ++kw) {
        int ti = t + kw - 1;
        if (ti < 0 || ti >= 2048) continue;
        short8 u = *(const short8*)&A1u[(((long)b * 2048 + ti) * 64 + fi) * 128 + ci8];
        int kk = kh * 3 + kw;
#pragma unroll
        for (int c = 0; c < 8; ++c)
          a[c] = fmaf(wreg[kk][c], b2f((unsigned short)u[c]), a[c]);
      }
    }
    short8 p;
#pragma unroll
    for (int c = 0; c < 8; ++c) p[c] = (short)f2bu(a[c]);
    *(short8*)&dw2s[f * 136 + ci8] = p;
  }
  for (int ct = 0; ct < 4; ++ct) {
    int co0 = ct * 64;
    __syncthreads();   // dw2s ready (ct=0) / red consumed (ct>0)
    for (int l2 = 0; l2 < 4; ++l2) {
      int idx = l2 * 256 + tid;
      int row = idx >> 4, koff = (idx & 15) * 8;
      *(short8*)&Bs[row * 136 + koff] =
          *(const short8*)&w2b[(long)(co0 + row) * 128 + koff];
    }
    if (tid < 64) {
      int co = co0 + tid;
      float s = g2[co] * rsqrtf(v2[co] + 1e-5f);
      ssc[tid] = s;
      ssh[tid] = b2[co] - m2[co] * s + s * pb[co];
    }
    __syncthreads();
    f32x4 zv = {0.f, 0.f, 0.f, 0.f};
    f32x4 acc[2][2] = {{zv, zv}, {zv, zv}};
#pragma unroll
    for (int kc = 0; kc < 4; ++kc) {
      short8 a0 = *(const short8*)&dw2s[(rw + l15) * 136 + kc * 32 + quad * 8];
      short8 a1 = *(const short8*)&dw2s[(rw + 16 + l15) * 136 + kc * 32 + quad * 8];
      short8 b0 = *(const short8*)&Bs[(cw + l15) * 136 + kc * 32 + quad * 8];
      short8 b1 = *(const short8*)&Bs[(cw + 16 + l15) * 136 + kc * 32 + quad * 8];
      acc[0][0] = __builtin_amdgcn_mfma_f32_16x16x32_bf16(a0, b0, acc[0][0], 0, 0, 0);
      acc[0][1] = __builtin_amdgcn_mfma_f32_16x16x32_bf16(a0, b1, acc[0][1], 0, 0, 0);
      acc[1][0] = __builtin_amdgcn_mfma_f32_16x16x32_bf16(a1, b0, acc[1][0], 0, 0, 0);
      acc[1][1] = __builtin_amdgcn_mfma_f32_16x16x32_bf16(a1, b1, acc[1][1], 0, 0, 0);
    }
#pragma unroll
    for (int mi = 0; mi < 2; ++mi)
#pragma unroll
      for (int nj = 0; nj < 2; ++nj) {
        int colg = cw + nj * 16 + l15;
        float s = ssc[colg], sh = ssh[colg];
        float sum = 0.f;
#pragma unroll
        for (int r = 0; r < 4; ++r) sum += fmaxf(fmaf(s, acc[mi][nj][r], sh), 0.f);
        int rowgroup = (wv >> 1) * 8 + mi * 4 + quad;
        red[rowgroup * 64 + colg] = sum;
      }
    __syncthreads();
    if (tid < 64) {
      float s = 0.f;
#pragma unroll
      for (int r = 0; r < 16; ++r) s += red[r * 64 + tid];
      float vo = s * (1.f / 64.f);
      unsigned short hi = f2bu(vo);
      unsigned short lo = f2bu(vo - b2f(hi));
      unsigned short* hp = (unsigned short*)hconv3 + (long)bt * 768 + co0 + tid;
      hp[0] = hi; hp[256] = lo; hp[512] = hi;
    }
  }
}

// ---------------------------------------------------------------------------
// FAVOR feature kernel (fused qf + kfT): F = relu(dn * X @ pm^T) + 1e-3.
// ---------------------------------------------------------------------------
__global__ __launch_bounds__(256) void favor_kernel(
    const bf16* __restrict__ qkvb, const bf16* __restrict__ pm,
    bf16* __restrict__ qf, bf16* __restrict__ kfT, float dn)
{
  __shared__ short As[4096];
  __shared__ short Bs[4096];
  int tid = threadIdx.x;
  int lane = tid & 63, w = tid >> 6;
  int quad = lane >> 4, l15 = lane & 15;
  int rw = (w >> 1) * 32, cw = (w & 1) * 32;
  int r0 = blockIdx.x * 64, n0 = blockIdx.y * 64;
  int z16 = blockIdx.z;
  bool isK = z16 >= 8;
  int z = z16 & 7, zb = z >> 2, zh = z & 3;
  const bf16* A = qkvb + (isK ? 256 : 0) + (long)zb * 1048576 + zh * 64;
  f32x4 zv = {0.f, 0.f, 0.f, 0.f};
  f32x4 acc[2][2] = {{zv, zv}, {zv, zv}};
  const bf16* Ag = A + (long)(r0 + (tid >> 2)) * 512 + ((tid & 3) * 8);
  const bf16* Bg = pm + (long)(n0 + (tid >> 2)) * 64 + ((tid & 3) * 8);
  llds16(Ag, &As[tid * 8]);
  llds16(Ag + 32, &As[tid * 8 + 2048]);
  llds16(Bg, &Bs[tid * 8]);
  llds16(Bg + 32, &Bs[tid * 8 + 2048]);
  __syncthreads();
#pragma unroll
  for (int c = 0; c < 2; ++c) {
    short8 a0 = *(const short8*)&As[c * 2048 + (rw + l15) * 32 + quad * 8];
    short8 a1 = *(const short8*)&As[c * 2048 + (rw + 16 + l15) * 32 + quad * 8];
    short8 b0 = *(const short8*)&Bs[c * 2048 + (cw + l15) * 32 + quad * 8];
    short8 b1 = *(const short8*)&Bs[c * 2048 + (cw + 16 + l15) * 32 + quad * 8];
    acc[0][0] = __builtin_amdgcn_mfma_f32_16x16x32_bf16(a0, b0, acc[0][0], 0, 0, 0);
    acc[0][1] = __builtin_amdgcn_mfma_f32_16x16x32_bf16(a0, b1, acc[0][1], 0, 0, 0);
    acc[1][0] = __builtin_amdgcn_mfma_f32_16x16x32_bf16(a1, b0, acc[1][0], 0, 0, 0);
    acc[1][1] = __builtin_amdgcn_mfma_f32_16x16x32_bf16(a1, b1, acc[1][1], 0, 0, 0);
  }
  bf16* qfz = qf + (long)zb * 3145728 + (long)zh * 786432;
  unsigned short* kfz = (unsigned short*)kfT + (long)zb * 3145728 + (long)zh * 786432;
#pragma unroll
  for (int mi = 0; mi < 2; ++mi)
#pragma unroll
    for (int nj = 0; nj < 2; ++nj) {
      int colg = n0 + cw + nj * 16 + l15;
      int rbase = r0 + rw + mi * 16 + quad * 4;
      float ov[4];
#pragma unroll
      for (int r = 0; r < 4; ++r)
        ov[r] = fmaxf(acc[mi][nj][r] * dn, 0.f) + 1e-3f;
      if (!isK) {
#pragma unroll
        for (int r = 0; r < 4; ++r)
          qfz[(long)(rbase + r) * 384 + colg] = __float2bfloat16(ov[r]);
      } else {
        ushort4 p;
        p.x = f2bu(ov[0]); p.y = f2bu(ov[1]); p.z = f2bu(ov[2]); p.w = f2bu(ov[3]);
        *(ushort4*)&kfz[(long)colg * 2048 + rbase] = p;
      }
    }
}

// ksum[z][j] = sum_t kfT[z][j][t]
__global__ __launch_bounds__(256) void rowsum_kernel(
    const bf16* __restrict__ kfT, float* __restrict__ ksum)
{
  int z = blockIdx.x;
  int j = blockIdx.y * 4 + (threadIdx.x >> 6);
  int lane = threadIdx.x & 63;
  const short* base = (const short*)kfT + ((long)z * 384 + j) * 2048;
  float acc = 0.f;
#pragma unroll
  for (int i = 0; i < 4; ++i) {
    short8 v = *(const short8*)&base[i * 512 + lane * 8];
#pragma unroll
    for (int e = 0; e < 8; ++e) acc += b2f((unsigned short)v[e]);
  }
#pragma unroll
  for (int o = 32; o > 0; o >>= 1) acc += __shfl_xor(acc, o, 64);
  if (lane == 0) ksum[z * 384 + j] = acc;
}

// ---------------------------------------------------------------------------
// MFMA bf16 GEMM: C = epi(A @ Bt^T).  A [M][K] bf16, Bt [N][K] bf16.
// EPI: 0 +bias | 3 acc*rowsc[row]
//      5 qkv split: col<512 -> C[row*512+col]; else vT (C2)
//      7 split-K: atomicAdd into f32 C (+bias once, at segment zh==0)
//      8 GLU -> A3 split out (ldc=3072) | 9 GLU -> single bf16 out
// ---------------------------------------------------------------------------
template <typename CTy, int EPI>
__global__ __launch_bounds__(256) void mgemm_kernel(
    const bf16* __restrict__ A, const bf16* __restrict__ Bt,
    const float* __restrict__ bias, const float* __restrict__ res,
    const float* __restrict__ rowsc, CTy* __restrict__ C, bf16* __restrict__ C2,
    int K, int lda, int ldbt, int ldc,
    long sAb, long sAh, long sBb, long sBh, long sCb, long sCh,
    long sRb, long sRh, int Hdiv, float alpha)
{
  constexpr bool DUALB = (EPI == 8 || EPI == 9);
  __shared__ short As[4096];
  __shared__ short Bs[4096];
  __shared__ short Bs2[DUALB ? 4096 : 8];
  int tid = threadIdx.x;
  int lane = tid & 63, w = tid >> 6;
  int quad = lane >> 4, l15 = lane & 15;
  int rw = (w >> 1) * 32, cw = (w & 1) * 32;
  int r0 = blockIdx.x * 64, n0 = blockIdx.y * 64;
  int zb = blockIdx.z / Hdiv, zh = blockIdx.z % Hdiv;
  A += zb * sAb + zh * sAh;
  Bt += zb * sBb + zh * sBh;
  C += zb * sCb + zh * sCh;
  if (res) res += zb * sCb + zh * sCh;
  const float* rsp = (EPI == 3) ? rowsc + zb * sRb + zh * sRh : nullptr;
  f32x4 zv = {0.f, 0.f, 0.f, 0.f};
  f32x4 acc[2][2] = {{zv, zv}, {zv, zv}};
  f32x4 acc2[2][2] = {{zv, zv}, {zv, zv}};
  const bf16* Ag = A + (long)(r0 + (tid >> 2)) * lda + ((tid & 3) * 8);
  const bf16* Bg = Bt + (long)(n0 + (tid >> 2)) * ldbt + ((tid & 3) * 8);
  const bf16* Bg2 = DUALB ? Bg + sRb : nullptr;
  short* Asd = &As[tid * 8];
  short* Bsd = &Bs[tid * 8];
  short* Bs2d = &Bs2[DUALB ? tid * 8 : 0];
  for (int k0 = 0; k0 < K; k0 += 64) {
    if (k0) __syncthreads();
    llds16(Ag + k0, Asd);
    llds16(Ag + k0 + 32, Asd + 2048);
    llds16(Bg + k0, Bsd);
    llds16(Bg + k0 + 32, Bsd + 2048);
    if constexpr (DUALB) {
      llds16(Bg2 + k0, Bs2d);
      llds16(Bg2 + k0 + 32, Bs2d + 2048);
    }
    __syncthreads();
#pragma unroll
    for (int c = 0; c < 2; ++c) {
      short8 a0 = *(const short8*)&As[c * 2048 + (rw + l15) * 32 + quad * 8];
      short8 a1 = *(const short8*)&As[c * 2048 + (rw + 16 + l15) * 32 + quad * 8];
      short8 b0 = *(const short8*)&Bs[c * 2048 + (cw + l15) * 32 + quad * 8];
      short8 b1 = *(const short8*)&Bs[c * 2048 + (cw + 16 + l15) * 32 + quad * 8];
      acc[0][0] = __builtin_amdgcn_mfma_f32_16x16x32_bf16(a0, b0, acc[0][0], 0, 0, 0);
      acc[0][1] = __builtin_amdgcn_mfma_f32_16x16x32_bf16(a0, b1, acc[0][1], 0, 0, 0);
      acc[1][0] = __builtin_amdgcn_mfma_f32_16x16x32_bf16(a1, b0, acc[1][0], 0, 0, 0);
      acc[1][1] = __builtin_amdgcn_mfma_f32_16x16x32_bf16(a1, b1, acc[1][1], 0, 0, 0);
      if constexpr (DUALB) {
        short8 c0 = *(const short8*)&Bs2[c * 2048 + (cw + l15) * 32 + quad * 8];
        short8 c1 = *(const short8*)&Bs2[c * 2048 + (cw + 16 + l15) * 32 + quad * 8];
        acc2[0][0] = __builtin_amdgcn_mfma_f32_16x16x32_bf16(a0, c0, acc2[0][0], 0, 0, 0);
        acc2[0][1] = __builtin_amdgcn_mfma_f32_16x16x32_bf16(a0, c1, acc2[0][1], 0, 0, 0);
        acc2[1][0] = __builtin_amdgcn_mfma_f32_16x16x32_bf16(a1, c0, acc2[1][0], 0, 0, 0);
        acc2[1][1] = __builtin_amdgcn_mfma_f32_16x16x32_bf16(a1, c1, acc2[1][1], 0, 0, 0);
      }
    }
  }
#pragma unroll
  for (int mi = 0; mi < 2; ++mi)
#pragma unroll
    for (int nj = 0; nj < 2; ++nj) {
      int colg = n0 + cw + nj * 16 + l15;
      float bv_ = bias ? bias[colg] : 0.f;
      float bv2 = DUALB ? bias[colg + 1024] : 0.f;
      int rbase = r0 + rw + mi * 16 + quad * 4;
      float ov[4];
#pragma unroll
      for (int r = 0; r < 4; ++r) {
        float v = acc[mi][nj][r];
        if constexpr (EPI == 0 || EPI == 5) {
          v += bv_;
        } else if constexpr (EPI == 3) {
          v *= rsp[rbase + r];
        } else if constexpr (EPI == 7) {
          if (zh == 0) v += bv_;   // bias exactly once across K-segments
        } else if constexpr (DUALB) {
          v = gelu_exact(v + bv_) * (acc2[mi][nj][r] + bv2);
        }
        ov[r] = v;
      }
      if constexpr (EPI == 5) {
        if (colg < 512) {
#pragma unroll
          for (int r = 0; r < 4; ++r) sto1(&C[(long)(rbase + r) * ldc + colg], ov[r]);
        } else {
          int bb = rbase >> 11, t0 = rbase & 2047;
          long off = (((long)bb * 4 + ((colg - 512) >> 6)) * 64 + (colg & 63)) * 2048 + t0;
          ushort4 p;
          p.x = f2bu(ov[0]); p.y = f2bu(ov[1]); p.z = f2bu(ov[2]); p.w = f2bu(ov[3]);
          *(ushort4*)((unsigned short*)C2 + off) = p;
        }
      } else if constexpr (EPI == 7) {
#pragma unroll
        for (int r = 0; r < 4; ++r)
          atomicAdd((float*)&C[(long)(rbase + r) * ldc + colg], ov[r]);
      } else if constexpr (EPI == 8) {
        unsigned short* Cu = (unsigned short*)C;
#pragma unroll
        for (int r = 0; r < 4; ++r) {
          float v = ov[r];
          unsigned short hi = f2bu(v);
          unsigned short lo = f2bu(v - b2f(hi));
          long rowo = (long)(rbase + r) * ldc;
          Cu[rowo + colg] = hi;
          Cu[rowo + 1024 + colg] = lo;
          Cu[rowo + 2048 + colg] = hi;
        }
      } else {
#pragma unroll
        for (int r = 0; r < 4; ++r) sto1(&C[(long)(rbase + r) * ldc + colg], ov[r]);
      }
    }
  (void)alpha;
}

// ---------------------------------------------------------------------------
// LayerNorm: one wave per row.  A3 mode writes split-3 bf16 rows (stride 3*DIM).
// ---------------------------------------------------------------------------
template <int DIM, bool RELU, bool ADDPOS, bool DUAL, bool A3, typename OTy>
__global__ __launch_bounds__(256) void ln_kernel(
    const float* __restrict__ in, const float* __restrict__ g,
    const float* __restrict__ b, const float* __restrict__ pos,
    OTy* __restrict__ out0, float* __restrict__ out1)
{
  constexpr int CH = DIM / 64;
  int row = blockIdx.x * 4 + (threadIdx.x >> 6);
  int lane = threadIdx.x & 63;
  const float* rp = in + (long)row * DIM + lane * CH;
  float v[CH];
#pragma unroll
  for (int i = 0; i < CH; ++i) v[i] = rp[i];
  float s = 0.f;
#pragma unroll
  for (int i = 0; i < CH; ++i) s += v[i];
#pragma unroll
  for (int o = 32; o > 0; o >>= 1) s += __shfl_xor(s, o, 64);
  float mean = s * (1.f / DIM);
  float q = 0.f;
#pragma unroll
  for (int i = 0; i < CH; ++i) { float d = v[i] - mean; q += d * d; }
#pragma unroll
  for (int o = 32; o > 0; o >>= 1) q += __shfl_xor(q, o, 64);
  float rstd = rsqrtf(q * (1.f / DIM) + 1e-5f);
  int t = row & 2047;
#pragma unroll
  for (int i = 0; i < CH; ++i) {
    int c = lane * CH + i;
    float o = (v[i] - mean) * rstd * g[c] + b[c];
    if constexpr (ADDPOS) o += pos[(long)t * DIM + c];
    if constexpr (RELU) o = fmaxf(o, 0.f);
    if constexpr (A3) {
      unsigned short hi = f2bu(o);
      unsigned short lo = f2bu(o - b2f(hi));
      unsigned short* op = (unsigned short*)out0 + (long)row * (3 * DIM) + c;
      op[0] = hi; op[DIM] = lo; op[2 * DIM] = hi;
    } else {
      sto1(&out0[(long)row * DIM + c], o);
      if constexpr (DUAL) out1[(long)row * DIM + c] = o;
    }
  }
}

__global__ __launch_bounds__(256) void dinv_kernel(
    const bf16* __restrict__ qf, const float* __restrict__ ksum,
    float* __restrict__ dinv)
{
  int z = blockIdx.x;
  int t = blockIdx.y * 4 + (threadIdx.x >> 6);
  int lane = threadIdx.x & 63;
  const bf16* qr = qf + ((long)z * 2048 + t) * 384;
  const float* ks = ksum + z * 384;
  float acc = 0.f;
#pragma unroll
  for (int i = 0; i < 6; ++i) {
    int j = lane + i * 64;
    acc = fmaf(tof(qr[j]), ks[j], acc);
  }
#pragma unroll
  for (int o = 32; o > 0; o >>= 1) acc += __shfl_xor(acc, o, 64);
  if (lane == 0) dinv[z * 2048 + t] = 1.f / acc;
}

__global__ __launch_bounds__(256) void clf2_kernel(
    const float* __restrict__ c2, const float* __restrict__ w,
    const float* __restrict__ b, float* __restrict__ out)
{
  int row = blockIdx.x * 4 + (threadIdx.x >> 6);
  int lane = threadIdx.x & 63;
  const float* rp = c2 + (long)row * 128 + lane * 2;
  float acc = rp[0] * w[lane * 2] + rp[1] * w[lane * 2 + 1];
#pragma unroll
  for (int o = 32; o > 0; o >>= 1) acc += __shfl_xor(acc, o, 64);
  if (lane == 0) out[row] = acc + b[0];
}

// ---------------------------------------------------------------------------
extern "C" void kernel_launch(void* const* d_in, const int* in_sizes, int n_in,
                              void* d_out, int out_size, void* d_ws, size_t ws_size,
                              hipStream_t stream)
{
  const float* X    = (const float*)d_in[0];
  const float* c0w  = (const float*)d_in[1];
  const float* d1w  = (const float*)d_in[2];
  const float* d1b  = (const float*)d_in[3];
  const float* p1w  = (const float*)d_in[4];
  const float* p1b  = (const float*)d_in[5];
  const float* g1   = (const float*)d_in[6];
  const float* b1   = (const float*)d_in[7];
  const float* m1   = (const float*)d_in[8];
  const float* v1   = (const float*)d_in[9];
  const float* d2w  = (const float*)d_in[10];
  const float* d2b  = (const float*)d_in[11];
  const float* p2w  = (const float*)d_in[12];
  const float* p2b  = (const float*)d_in[13];
  const float* g2   = (const float*)d_in[14];
  const float* b2   = (const float*)d_in[15];
  const float* m2   = (const float*)d_in[16];
  const float* v2   = (const float*)d_in[17];
  const float* projw= (const float*)d_in[18];
  const float* projb= (const float*)d_in[19];
  const float* ln0g = (const float*)d_in[20];
  const float* ln0b = (const float*)d_in[21];
  const float* pos  = (const float*)d_in[22];
  const float* ln1g = (const float*)d_in[23];
  const float* ln1b = (const float*)d_in[24];
  const float* wq   = (const float*)d_in[25];
  const float* bq   = (const float*)d_in[26];
  const float* wk   = (const float*)d_in[27];
  const float* bk   = (const float*)d_in[28];
  const float* wv   = (const float*)d_in[29];
  const float* bv   = (const float*)d_in[30];
  const float* wo   = (const float*)d_in[31];
  const float* bo   = (const float*)d_in[32];
  const float* pmat = (const float*)d_in[33];
  const float* ln2g = (const float*)d_in[34];
  const float* ln2b = (const float*)d_in[35];
  const float* ffw1 = (const float*)d_in[36];
  const float* ffb1 = (const float*)d_in[37];
  const float* ffw2 = (const float*)d_in[38];
  const float* ffb2 = (const float*)d_in[39];
  const float* cw1  = (const float*)d_in[40];
  const float* cb1  = (const float*)d_in[41];
  const float* clng = (const float*)d_in[42];
  const float* clnb = (const float*)d_in[43];
  const float* cw2  = (const float*)d_in[44];
  const float* cb2  = (const float*)d_in[45];
  (void)in_sizes; (void)n_in; (void)out_size; (void)ws_size;

  // ---- workspace (float-slot offsets); within 88.9 MB envelope ----
  float* ws     = (float*)d_ws;
  float* x1     = ws;                          // 1,048,576
  float* x2     = ws + 1048576;                // 1,048,576
  bf16*  lnb16  = (bf16*)(ws + 2097152);       // [4096][256] single (ln1/ln2 out)
  bf16*  hconv3 = (bf16*)(ws + 3670016);       // [4096][768] A3
  // --- arena @5,242,880: A1 during conv; weights+scratch after ---
  bf16*  A1     = (bf16*)(ws + 5242880);       // [4096][64][128], conv only
  bf16*  wqkv1  = (bf16*)(ws + 5242880);       // [4][768][256] single (post-conv)
  float* qkvbias= ws + 6422528;                // [4][768]
  bf16*  f1w1   = (bf16*)(ws + 6425600);       // [4][2048][256] single
  bf16*  f2w1   = (bf16*)(ws + 9571328);       // [4][256][1024] single
  bf16*  wo_bf  = (bf16*)(ws + 11144192);      // [4][256][256]
  bf16*  pm_bf  = (bf16*)(ws + 11275264);      // [4][384][64]
  bf16*  projwT3= (bf16*)(ws + 11324416);      // [256][768]
  bf16*  cw1T3  = (bf16*)(ws + 11422720);      // [128][768]
  bf16*  qkvb   = (bf16*)(ws + 11471872);      // [4096][512] (q,k)
  bf16*  vT     = (bf16*)(ws + 12520448);      // [8][64][2048]
  bf16*  qf     = (bf16*)(ws + 13044736);      // [8][2048][384]
  bf16*  kfT    = (bf16*)(ws + 16190464);      // [8][384][2048]
  bf16*  obufb  = (bf16*)(ws + 19336192);      // [4096][256]
  float* ctx32  = ws + 19860480;               // [8][64][384] fp32
  float* ksum   = ws + 20057088;               // 4096
  float* dinvp  = ws + 20061184;               // 16384
  bf16*  ctxb   = (bf16*)(ws + 20077568);      // [8][64][384] bf16
  float* lnb32  = ws + 20126720;               // [4096][256] (proj out)
  float* c1     = ws + 21175296;               // [4096][128]
  float* c2     = ws + 21699584;               // [4096][128]
  bf16*  gb2    = qkvb;                        // [4096][1024] single (overlay)
  bf16*  sbuf3  = qkvb;                        // [4096][768] A3 (classifier overlay)
  bf16*  pw2_bf = (bf16*)x1;                   // [256][128] pre-conv temp

  const float dn = 0.35355339059327378f;  // 64^-0.25

  // --- conv frontend (pw2_bf staged in x1's slot; x1 written later by ln0) ---
  f2b_kernel<<<128, 256, 0, stream>>>(p2w, pw2_bf, 32768);
  front1_kernel<<<4096, 256, 0, stream>>>(X, c0w, d1w, d1b, p1w, p1b, g1, b1, m1, v1, A1);
  convtail_kernel<<<4096, 256, 0, stream>>>(A1, d2w, d2b, pw2_bf, p2b, g2, b2, m2, v2, hconv3);

  // --- weight conversion (A1 dead; weights live in its span) ---
  pack_qkv1_kernel<<<3072, 256, 0, stream>>>(wq, wk, wv, wqkv1);
  pack_qkvbias_kernel<<<12, 256, 0, stream>>>(bq, bk, bv, qkvbias);
  tconv_kernel<<<dim3(2048, 1, 4), 256, 0, stream>>>(ffw1, f1w1, 256, 2048, 524288, 524288);
  tconv_kernel<<<dim3(1024, 1, 4), 256, 0, stream>>>(ffw2, f2w1, 1024, 256, 262144, 262144);
  tconv_kernel<<<dim3(256, 1, 4), 256, 0, stream>>>(wo, wo_bf, 256, 256, 65536, 65536);
  tconv3_kernel<<<dim3(256, 1, 1), 256, 0, stream>>>(projw, projwT3, 256, 256, 65536, 196608);
  tconv3_kernel<<<dim3(128, 1, 1), 256, 0, stream>>>(cw1, cw1T3, 256, 128, 32768, 98304);
  f2b_kernel<<<384, 256, 0, stream>>>(pmat, pm_bf, 98304);

  // proj (split-3, K=768) + ln0 + pos -> x1 = x2
  mgemm_kernel<float, 0><<<dim3(64, 4, 1), 256, 0, stream>>>(
      hconv3, projwT3, projb, nullptr, nullptr, lnb32, nullptr,
      768, 768, 768, 256, 0, 0, 0, 0, 0, 0, 0, 0, 1, 1.f);
  ln_kernel<256, false, true, true, false, float><<<1024, 256, 0, stream>>>(
      lnb32, ln0g, ln0b, pos, x1, x2);

  for (int l = 0; l < 4; ++l) {
    const bf16* wqkv_l = wqkv1 + (size_t)l * 196608;
    const float* qb_l  = qkvbias + l * 768;
    const bf16* pm_l   = pm_bf + (size_t)l * 24576;
    const bf16* wo_l   = wo_bf + (size_t)l * 65536;
    const float* bov   = bo + l * 256;
    const bf16* f1w_l  = f1w1 + (size_t)l * 524288;
    const float* f1b_l = ffb1 + l * 2048;
    const bf16* f2w_l  = f2w1 + (size_t)l * 262144;
    const float* f2b_l = ffb2 + l * 256;

    // a = LN(x2) -> single bf16
    ln_kernel<256, false, false, false, false, bf16><<<1024, 256, 0, stream>>>(
        x2, ln1g + l * 256, ln1b + l * 256, nullptr, lnb16, nullptr);
    // qkv (single-bf16, K=256)
    mgemm_kernel<bf16, 5><<<dim3(64, 12, 1), 256, 0, stream>>>(
        lnb16, wqkv_l, qb_l, nullptr, nullptr, qkvb, vT,
        256, 256, 256, 512, 0, 0, 0, 0, 0, 0, 0, 0, 1, 1.f);
    // zero ctx32
    zero4_kernel<<<192, 256, 0, stream>>>(ctx32);
    // fused FAVOR: qf (row) + kfT (transposed)
    favor_kernel<<<dim3(32, 6, 16), 256, 0, stream>>>(
        qkvb, pm_l, qf, kfT, dn);
    rowsum_kernel<<<dim3(8, 96), 256, 0, stream>>>(kfT, ksum);
    dinv_kernel<<<dim3(8, 512), 256, 0, stream>>>(qf, ksum, dinvp);
    // ctx split-K: 16 segments of 128 over t (3 blocks/CU)
    mgemm_kernel<float, 7><<<dim3(1, 6, 128), 256, 0, stream>>>(
        vT, kfT, nullptr, nullptr, nullptr, ctx32, nullptr,
        128, 2048, 2048, 384, 131072, 128, 786432, 128, 24576, 0, 0, 0, 16, 1.f);
    f2b_kernel<<<768, 256, 0, stream>>>(ctx32, ctxb, 196608);
    // o = (qf @ ctxb^T) * dinv -> obufb
    mgemm_kernel<bf16, 3><<<dim3(32, 1, 8), 256, 0, stream>>>(
        qf, ctxb, nullptr, nullptr, dinvp, obufb, nullptr,
        384, 384, 384, 256, 3145728, 786432, 98304, 24576, 524288, 64, 8192, 2048, 4, 1.f);
    // x1 += o @ wo + bo   (split-K x4, K=64/seg, atomic)
    mgemm_kernel<float, 7><<<dim3(64, 4, 4), 256, 0, stream>>>(
        obufb, wo_l, bov, nullptr, nullptr, x1, nullptr,
        64, 256, 256, 256, 0, 64, 0, 64, 0, 0, 0, 0, 4, 1.f);
    // f = LN(x1) -> single bf16
    ln_kernel<256, false, false, false, false, bf16><<<1024, 256, 0, stream>>>(
        x1, ln2g + l * 256, ln2b + l * 256, nullptr, lnb16, nullptr);
    // gb2 = gelu(f@W1a+b1a)*(f@W1b+b1b)  (single-bf16, EPI9, ldc=1024)
    mgemm_kernel<bf16, 9><<<dim3(64, 16, 1), 256, 0, stream>>>(
        lnb16, f1w_l, f1b_l, nullptr, nullptr, gb2, nullptr,
        256, 256, 256, 1024, 0, 0, 0, 0, 0, 0, 262144, 0, 1, 1.f);
    // x2 += gb2 @ ffw2 + b   (single-bf16, K=1024 as 4x256, atomic)
    mgemm_kernel<float, 7><<<dim3(64, 4, 4), 256, 0, stream>>>(
        gb2, f2w_l, f2b_l, nullptr, nullptr, x2, nullptr,
        256, 1024, 1024, 256, 0, 256, 0, 256, 0, 0, 0, 0, 4, 1.f);
  }

  // classifier (split-3 input)
  sumb3_kernel<<<4096, 256, 0, stream>>>(x1, x2, sbuf3);
  mgemm_kernel<float, 0><<<dim3(64, 2, 1), 256, 0, stream>>>(
      sbuf3, cw1T3, cb1, nullptr, nullptr, c1, nullptr,
      768, 768, 768, 128, 0, 0, 0, 0, 0, 0, 0, 0, 1, 1.f);
  ln_kernel<128, true, false, false, false, float><<<1024, 256, 0, stream>>>(
      c1, clng, clnb, nullptr, c2, nullptr);
  clf2_kernel<<<1024, 256, 0, stream>>>(c2, cw2, cb2, (float*)d_out);
}

// Round 15
// 683.162 us; speedup vs baseline: 1.0840x; 1.0840x over previous
//
#include <hip/hip_runtime.h>
#include <hip/hip_bf16.h>
#include <math.h>

using bf16 = __hip_bfloat16;
typedef __attribute__((ext_vector_type(8))) short short8;
typedef __attribute__((ext_vector_type(4))) float f32x4;

__device__ __forceinline__ float tof(float x) { return x; }
__device__ __forceinline__ float tof(bf16 x) { return __bfloat162float(x); }
__device__ __forceinline__ float b2f(unsigned short u) {
  union { float f; unsigned int i; } c; c.i = ((unsigned int)u) << 16; return c.f;
}
__device__ __forceinline__ unsigned short f2bu(float v) {
  bf16 h = __float2bfloat16(v);
  return *(unsigned short*)&h;
}
__device__ __forceinline__ void sto1(float* p, float v) { *p = v; }
__device__ __forceinline__ void sto1(bf16* p, float v) { *p = __float2bfloat16(v); }

__device__ __forceinline__ float gelu_exact(float x) {
  return 0.5f * x * (1.f + erff(x * 0.70710678118654752f));
}

// async global->LDS, 16B/lane; LDS dest = wave base + lane*16 (m97 pattern).
__device__ __forceinline__ void llds16(const bf16* g, short* l) {
  __builtin_amdgcn_global_load_lds((const __attribute__((address_space(1))) void*)g,
                                   (__attribute__((address_space(3))) void*)l, 16, 0, 0);
}

// ---------------------------------------------------------------------------
// Split-3 convention (fp32-faithful bf16 GEMM via K-extension) retained ONLY
// for proj (hconv3) and classifier (sbuf3). qkv/ff1/ff2 single-bf16 (floor
// 2^-7 constant across all de-splits, R1-R13). Split-K depth: 2 segments for
// wo/ff2, 8 for ctx — R14 proved deeper splits lose to atomic contention.
// ---------------------------------------------------------------------------

// wqkv1[l][n(768)][k(256)] = bf16(w[l][k][n & 255]), single-bf16.
__global__ __launch_bounds__(256) void pack_qkv1_kernel(
    const float* __restrict__ wq, const float* __restrict__ wk,
    const float* __restrict__ wv, bf16* __restrict__ out)
{
  int idx = blockIdx.x * 256 + threadIdx.x;   // < 4*768*256
  int k = idx & 255;
  int nl = idx >> 8;
  int n = nl % 768, l = nl / 768;
  const float* src = (n < 256) ? wq : (n < 512 ? wk : wv);
  out[(long)l * 196608 + (long)n * 256 + k] =
      __float2bfloat16(src[(long)l * 65536 + k * 256 + (n & 255)]);
}

__global__ __launch_bounds__(256) void pack_qkvbias_kernel(
    const float* __restrict__ bq, const float* __restrict__ bk,
    const float* __restrict__ bv, float* __restrict__ out)
{
  int i = blockIdx.x * 256 + threadIdx.x;   // < 3072
  if (i >= 3072) return;
  int n = i % 768, l = i / 768;
  const float* src = (n < 256) ? bq : (n < 512 ? bk : bv);
  out[i] = src[l * 256 + (n & 255)];
}

// out[l][n][k] = in[l][k][n], bf16 (single)
__global__ __launch_bounds__(256) void tconv_kernel(
    const float* __restrict__ in, bf16* __restrict__ out,
    int K, int N, long sin, long sout)
{
  int l = blockIdx.z;
  int idx = blockIdx.x * 256 + threadIdx.x;
  int k = idx % K, n = idx / K;
  out[l * sout + idx] = __float2bfloat16(in[l * sin + (long)k * N + n]);
}

// out[l][n][3K] = B3-split of in[l][k][n]
__global__ __launch_bounds__(256) void tconv3_kernel(
    const float* __restrict__ in, bf16* __restrict__ out,
    int K, int N, long sin, long sout)
{
  int l = blockIdx.z;
  int idx = blockIdx.x * 256 + threadIdx.x;
  int k = idx % K, n = idx / K;
  float v = in[l * sin + (long)k * N + n];
  unsigned short hi = f2bu(v);
  unsigned short lo = f2bu(v - b2f(hi));
  unsigned short* o = (unsigned short*)out + l * sout + (long)n * (3 * K);
  o[k] = hi; o[K + k] = hi; o[2 * K + k] = lo;
}

__global__ __launch_bounds__(256) void f2b_kernel(
    const float* __restrict__ in, bf16* __restrict__ out, int n)
{
  int i = blockIdx.x * 256 + threadIdx.x;
  if (i < n) out[i] = __float2bfloat16(in[i]);
}

__global__ __launch_bounds__(256) void zero4_kernel(float* __restrict__ p) {
  int i = (blockIdx.x * 256 + threadIdx.x) * 4;
  float4 z; z.x = 0.f; z.y = 0.f; z.z = 0.f; z.w = 0.f;
  *(float4*)&p[i] = z;
}

// s = x1 + x2 -> A3 split (classifier input), one row per block
__global__ __launch_bounds__(256) void sumb3_kernel(
    const float* __restrict__ a, const float* __restrict__ b, bf16* __restrict__ o)
{
  int row = blockIdx.x, c = threadIdx.x;
  long i = (long)row * 256 + c;
  float v = a[i] + b[i];
  unsigned short hi = f2bu(v);
  unsigned short lo = f2bu(v - b2f(hi));
  unsigned short* op = (unsigned short*)o + (long)row * 768 + c;
  op[0] = hi; op[256] = lo; op[512] = hi;
}

// ---------------------------------------------------------------------------
// Conv frontend stage 1: conv0+dw1+pw1+bn1+relu -> A1[b][t][f][ci] bf16
// ---------------------------------------------------------------------------
__global__ __launch_bounds__(256) void front1_kernel(
    const float* __restrict__ x, const float* __restrict__ c0w,
    const float* __restrict__ d1w, const float* __restrict__ d1b,
    const float* __restrict__ p1w, const float* __restrict__ p1b,
    const float* __restrict__ g1, const float* __restrict__ b1,
    const float* __restrict__ m1, const float* __restrict__ v1,
    bf16* __restrict__ A1)
{
  __shared__ float sd[256];
  __shared__ float ss[128], st[128], sb[128];
  int tid = threadIdx.x;
  int bt = ((blockIdx.x & 7) << 9) | (blockIdx.x >> 3);   // XCD swizzle
  int b = bt >> 11, t = bt & 2047;
  if (tid < 128) {
    float s = g1[tid] * rsqrtf(v1[tid] + 1e-5f);
    ss[tid] = s;
    st[tid] = b1[tid] - m1[tid] * s;
    sb[tid] = p1b[tid];
  }
  {
    int c = tid >> 6, f = tid & 63;
    float cw = c0w[c];
    float acc = d1b[c];
#pragma unroll
    for (int kh = 0; kh < 3; ++kh) {
      int fi = f + kh - 1;
      if (fi < 0 || fi >= 64) continue;
#pragma unroll
      for (int kw = 0; kw < 3; ++kw) {
        int ti = t + kw - 1;
        if (ti < 0 || ti >= 2048) continue;
        acc += d1w[c * 9 + kh * 3 + kw] * cw * x[((long)b * 2048 + ti) * 64 + fi];
      }
    }
    sd[c * 64 + f] = acc;
  }
  int ci0 = (tid * 8) & 127;
  float wreg[8][4];
#pragma unroll
  for (int j = 0; j < 8; ++j) {
    f32x4 w4 = *(const f32x4*)&p1w[(ci0 + j) * 4];
#pragma unroll
    for (int c = 0; c < 4; ++c) wreg[j][c] = w4[c];
  }
  __syncthreads();
  float ssr[8], str[8], sbr[8];
#pragma unroll
  for (int j = 0; j < 8; ++j) {
    ssr[j] = ss[ci0 + j]; str[j] = st[ci0 + j]; sbr[j] = sb[ci0 + j];
  }
  long ob = (long)bt * 8192;
  unsigned short* A1u = (unsigned short*)A1;
#pragma unroll
  for (int it = 0; it < 4; ++it) {
    int f = it * 16 + (tid >> 4);
    float sdv[4];
#pragma unroll
    for (int c = 0; c < 4; ++c) sdv[c] = sd[c * 64 + f];
    short8 pkt;
#pragma unroll
    for (int j = 0; j < 8; ++j) {
      float pre = sbr[j];
#pragma unroll
      for (int c = 0; c < 4; ++c) pre = fmaf(wreg[j][c], sdv[c], pre);
      pkt[j] = (short)f2bu(fmaxf(fmaf(ssr[j], pre, str[j]), 0.f));
    }
    *(short8*)&A1u[ob + it * 2048 + tid * 8] = pkt;
  }
}

// ---------------------------------------------------------------------------
// Conv tail (measured-best design, ~96us): dw2 (VALU) -> dw2s LDS; pw2 (MFMA)
// with Bs-staged weights; bn2+relu+mean(f) -> hconv3 A3 split. XCD swizzle.
// ---------------------------------------------------------------------------
__global__ __launch_bounds__(256, 4) void convtail_kernel(
    const bf16* __restrict__ A1, const float* __restrict__ w,
    const float* __restrict__ wb, const bf16* __restrict__ w2b,
    const float* __restrict__ pb, const float* __restrict__ g2,
    const float* __restrict__ b2, const float* __restrict__ m2,
    const float* __restrict__ v2, bf16* __restrict__ hconv3)
{
  __shared__ short dw2s[64 * 136];
  __shared__ short Bs[64 * 136];
  __shared__ float red[1024];
  __shared__ float ssc[64], ssh[64];
  int tid = threadIdx.x;
  int lane = tid & 63, wv = tid >> 6;
  int quad = lane >> 4, l15 = lane & 15;
  int rw = (wv >> 1) * 32, cw = (wv & 1) * 32;
  int bt = ((blockIdx.x & 7) << 9) | (blockIdx.x >> 3);   // XCD swizzle
  int b = bt >> 11, t = bt & 2047;
  int ci8 = (tid & 15) * 8;
  float wreg[9][8], breg[8];
#pragma unroll
  for (int c = 0; c < 8; ++c) {
    breg[c] = wb[ci8 + c];
#pragma unroll
    for (int kk = 0; kk < 9; ++kk) wreg[kk][c] = w[(ci8 + c) * 9 + kk];
  }
  const unsigned short* A1u = (const unsigned short*)A1;
  for (int pass = 0; pass < 4; ++pass) {
    int f = pass * 16 + (tid >> 4);
    float a[8];
#pragma unroll
    for (int c = 0; c < 8; ++c) a[c] = breg[c];
#pragma unroll
    for (int kh = 0; kh < 3; ++kh) {
      int fi = f + kh - 1;
      if (fi < 0 || fi >= 64) continue;
#pragma unroll
      for (int kw = 0; kw < 3; ++kw) {
        int ti = t + kw - 1;
        if (ti < 0 || ti >= 2048) continue;
        short8 u = *(const short8*)&A1u[(((long)b * 2048 + ti) * 64 + fi) * 128 + ci8];
        int kk = kh * 3 + kw;
#pragma unroll
        for (int c = 0; c < 8; ++c)
          a[c] = fmaf(wreg[kk][c], b2f((unsigned short)u[c]), a[c]);
      }
    }
    short8 p;
#pragma unroll
    for (int c = 0; c < 8; ++c) p[c] = (short)f2bu(a[c]);
    *(short8*)&dw2s[f * 136 + ci8] = p;
  }
  for (int ct = 0; ct < 4; ++ct) {
    int co0 = ct * 64;
    __syncthreads();   // dw2s ready (ct=0) / red consumed (ct>0)
    for (int l2 = 0; l2 < 4; ++l2) {
      int idx = l2 * 256 + tid;
      int row = idx >> 4, koff = (idx & 15) * 8;
      *(short8*)&Bs[row * 136 + koff] =
          *(const short8*)&w2b[(long)(co0 + row) * 128 + koff];
    }
    if (tid < 64) {
      int co = co0 + tid;
      float s = g2[co] * rsqrtf(v2[co] + 1e-5f);
      ssc[tid] = s;
      ssh[tid] = b2[co] - m2[co] * s + s * pb[co];
    }
    __syncthreads();
    f32x4 zv = {0.f, 0.f, 0.f, 0.f};
    f32x4 acc[2][2] = {{zv, zv}, {zv, zv}};
#pragma unroll
    for (int kc = 0; kc < 4; ++kc) {
      short8 a0 = *(const short8*)&dw2s[(rw + l15) * 136 + kc * 32 + quad * 8];
      short8 a1 = *(const short8*)&dw2s[(rw + 16 + l15) * 136 + kc * 32 + quad * 8];
      short8 b0 = *(const short8*)&Bs[(cw + l15) * 136 + kc * 32 + quad * 8];
      short8 b1 = *(const short8*)&Bs[(cw + 16 + l15) * 136 + kc * 32 + quad * 8];
      acc[0][0] = __builtin_amdgcn_mfma_f32_16x16x32_bf16(a0, b0, acc[0][0], 0, 0, 0);
      acc[0][1] = __builtin_amdgcn_mfma_f32_16x16x32_bf16(a0, b1, acc[0][1], 0, 0, 0);
      acc[1][0] = __builtin_amdgcn_mfma_f32_16x16x32_bf16(a1, b0, acc[1][0], 0, 0, 0);
      acc[1][1] = __builtin_amdgcn_mfma_f32_16x16x32_bf16(a1, b1, acc[1][1], 0, 0, 0);
    }
#pragma unroll
    for (int mi = 0; mi < 2; ++mi)
#pragma unroll
      for (int nj = 0; nj < 2; ++nj) {
        int colg = cw + nj * 16 + l15;
        float s = ssc[colg], sh = ssh[colg];
        float sum = 0.f;
#pragma unroll
        for (int r = 0; r < 4; ++r) sum += fmaxf(fmaf(s, acc[mi][nj][r], sh), 0.f);
        int rowgroup = (wv >> 1) * 8 + mi * 4 + quad;
        red[rowgroup * 64 + colg] = sum;
      }
    __syncthreads();
    if (tid < 64) {
      float s = 0.f;
#pragma unroll
      for (int r = 0; r < 16; ++r) s += red[r * 64 + tid];
      float vo = s * (1.f / 64.f);
      unsigned short hi = f2bu(vo);
      unsigned short lo = f2bu(vo - b2f(hi));
      unsigned short* hp = (unsigned short*)hconv3 + (long)bt * 768 + co0 + tid;
      hp[0] = hi; hp[256] = lo; hp[512] = hi;
    }
  }
}

// ---------------------------------------------------------------------------
// FAVOR feature kernel (fused qf + kfT): F = relu(dn * X @ pm^T) + 1e-3.
// ---------------------------------------------------------------------------
__global__ __launch_bounds__(256) void favor_kernel(
    const bf16* __restrict__ qkvb, const bf16* __restrict__ pm,
    bf16* __restrict__ qf, bf16* __restrict__ kfT, float dn)
{
  __shared__ short As[4096];
  __shared__ short Bs[4096];
  int tid = threadIdx.x;
  int lane = tid & 63, w = tid >> 6;
  int quad = lane >> 4, l15 = lane & 15;
  int rw = (w >> 1) * 32, cw = (w & 1) * 32;
  int r0 = blockIdx.x * 64, n0 = blockIdx.y * 64;
  int z16 = blockIdx.z;
  bool isK = z16 >= 8;
  int z = z16 & 7, zb = z >> 2, zh = z & 3;
  const bf16* A = qkvb + (isK ? 256 : 0) + (long)zb * 1048576 + zh * 64;
  f32x4 zv = {0.f, 0.f, 0.f, 0.f};
  f32x4 acc[2][2] = {{zv, zv}, {zv, zv}};
  const bf16* Ag = A + (long)(r0 + (tid >> 2)) * 512 + ((tid & 3) * 8);
  const bf16* Bg = pm + (long)(n0 + (tid >> 2)) * 64 + ((tid & 3) * 8);
  llds16(Ag, &As[tid * 8]);
  llds16(Ag + 32, &As[tid * 8 + 2048]);
  llds16(Bg, &Bs[tid * 8]);
  llds16(Bg + 32, &Bs[tid * 8 + 2048]);
  __syncthreads();
#pragma unroll
  for (int c = 0; c < 2; ++c) {
    short8 a0 = *(const short8*)&As[c * 2048 + (rw + l15) * 32 + quad * 8];
    short8 a1 = *(const short8*)&As[c * 2048 + (rw + 16 + l15) * 32 + quad * 8];
    short8 b0 = *(const short8*)&Bs[c * 2048 + (cw + l15) * 32 + quad * 8];
    short8 b1 = *(const short8*)&Bs[c * 2048 + (cw + 16 + l15) * 32 + quad * 8];
    acc[0][0] = __builtin_amdgcn_mfma_f32_16x16x32_bf16(a0, b0, acc[0][0], 0, 0, 0);
    acc[0][1] = __builtin_amdgcn_mfma_f32_16x16x32_bf16(a0, b1, acc[0][1], 0, 0, 0);
    acc[1][0] = __builtin_amdgcn_mfma_f32_16x16x32_bf16(a1, b0, acc[1][0], 0, 0, 0);
    acc[1][1] = __builtin_amdgcn_mfma_f32_16x16x32_bf16(a1, b1, acc[1][1], 0, 0, 0);
  }
  bf16* qfz = qf + (long)zb * 3145728 + (long)zh * 786432;
  unsigned short* kfz = (unsigned short*)kfT + (long)zb * 3145728 + (long)zh * 786432;
#pragma unroll
  for (int mi = 0; mi < 2; ++mi)
#pragma unroll
    for (int nj = 0; nj < 2; ++nj) {
      int colg = n0 + cw + nj * 16 + l15;
      int rbase = r0 + rw + mi * 16 + quad * 4;
      float ov[4];
#pragma unroll
      for (int r = 0; r < 4; ++r)
        ov[r] = fmaxf(acc[mi][nj][r] * dn, 0.f) + 1e-3f;
      if (!isK) {
#pragma unroll
        for (int r = 0; r < 4; ++r)
          qfz[(long)(rbase + r) * 384 + colg] = __float2bfloat16(ov[r]);
      } else {
        ushort4 p;
        p.x = f2bu(ov[0]); p.y = f2bu(ov[1]); p.z = f2bu(ov[2]); p.w = f2bu(ov[3]);
        *(ushort4*)&kfz[(long)colg * 2048 + rbase] = p;
      }
    }
}

// ksum[z][j] = sum_t kfT[z][j][t]
__global__ __launch_bounds__(256) void rowsum_kernel(
    const bf16* __restrict__ kfT, float* __restrict__ ksum)
{
  int z = blockIdx.x;
  int j = blockIdx.y * 4 + (threadIdx.x >> 6);
  int lane = threadIdx.x & 63;
  const short* base = (const short*)kfT + ((long)z * 384 + j) * 2048;
  float acc = 0.f;
#pragma unroll
  for (int i = 0; i < 4; ++i) {
    short8 v = *(const short8*)&base[i * 512 + lane * 8];
#pragma unroll
    for (int e = 0; e < 8; ++e) acc += b2f((unsigned short)v[e]);
  }
#pragma unroll
  for (int o = 32; o > 0; o >>= 1) acc += __shfl_xor(acc, o, 64);
  if (lane == 0) ksum[z * 384 + j] = acc;
}

// ---------------------------------------------------------------------------
// MFMA bf16 GEMM: C = epi(A @ Bt^T).  A [M][K] bf16, Bt [N][K] bf16.
// EPI: 0 +bias | 3 acc*rowsc[row]
//      5 qkv split: col<512 -> C[row*512+col]; else vT (C2)
//      7 split-K: atomicAdd into f32 C (+bias once, at segment zh==0)
//      8 GLU -> A3 split out (ldc=3072) | 9 GLU -> single bf16 out
// ---------------------------------------------------------------------------
template <typename CTy, int EPI>
__global__ __launch_bounds__(256) void mgemm_kernel(
    const bf16* __restrict__ A, const bf16* __restrict__ Bt,
    const float* __restrict__ bias, const float* __restrict__ res,
    const float* __restrict__ rowsc, CTy* __restrict__ C, bf16* __restrict__ C2,
    int K, int lda, int ldbt, int ldc,
    long sAb, long sAh, long sBb, long sBh, long sCb, long sCh,
    long sRb, long sRh, int Hdiv, float alpha)
{
  constexpr bool DUALB = (EPI == 8 || EPI == 9);
  __shared__ short As[4096];
  __shared__ short Bs[4096];
  __shared__ short Bs2[DUALB ? 4096 : 8];
  int tid = threadIdx.x;
  int lane = tid & 63, w = tid >> 6;
  int quad = lane >> 4, l15 = lane & 15;
  int rw = (w >> 1) * 32, cw = (w & 1) * 32;
  int r0 = blockIdx.x * 64, n0 = blockIdx.y * 64;
  int zb = blockIdx.z / Hdiv, zh = blockIdx.z % Hdiv;
  A += zb * sAb + zh * sAh;
  Bt += zb * sBb + zh * sBh;
  C += zb * sCb + zh * sCh;
  if (res) res += zb * sCb + zh * sCh;
  const float* rsp = (EPI == 3) ? rowsc + zb * sRb + zh * sRh : nullptr;
  f32x4 zv = {0.f, 0.f, 0.f, 0.f};
  f32x4 acc[2][2] = {{zv, zv}, {zv, zv}};
  f32x4 acc2[2][2] = {{zv, zv}, {zv, zv}};
  const bf16* Ag = A + (long)(r0 + (tid >> 2)) * lda + ((tid & 3) * 8);
  const bf16* Bg = Bt + (long)(n0 + (tid >> 2)) * ldbt + ((tid & 3) * 8);
  const bf16* Bg2 = DUALB ? Bg + sRb : nullptr;
  short* Asd = &As[tid * 8];
  short* Bsd = &Bs[tid * 8];
  short* Bs2d = &Bs2[DUALB ? tid * 8 : 0];
  for (int k0 = 0; k0 < K; k0 += 64) {
    if (k0) __syncthreads();
    llds16(Ag + k0, Asd);
    llds16(Ag + k0 + 32, Asd + 2048);
    llds16(Bg + k0, Bsd);
    llds16(Bg + k0 + 32, Bsd + 2048);
    if constexpr (DUALB) {
      llds16(Bg2 + k0, Bs2d);
      llds16(Bg2 + k0 + 32, Bs2d + 2048);
    }
    __syncthreads();
#pragma unroll
    for (int c = 0; c < 2; ++c) {
      short8 a0 = *(const short8*)&As[c * 2048 + (rw + l15) * 32 + quad * 8];
      short8 a1 = *(const short8*)&As[c * 2048 + (rw + 16 + l15) * 32 + quad * 8];
      short8 b0 = *(const short8*)&Bs[c * 2048 + (cw + l15) * 32 + quad * 8];
      short8 b1 = *(const short8*)&Bs[c * 2048 + (cw + 16 + l15) * 32 + quad * 8];
      acc[0][0] = __builtin_amdgcn_mfma_f32_16x16x32_bf16(a0, b0, acc[0][0], 0, 0, 0);
      acc[0][1] = __builtin_amdgcn_mfma_f32_16x16x32_bf16(a0, b1, acc[0][1], 0, 0, 0);
      acc[1][0] = __builtin_amdgcn_mfma_f32_16x16x32_bf16(a1, b0, acc[1][0], 0, 0, 0);
      acc[1][1] = __builtin_amdgcn_mfma_f32_16x16x32_bf16(a1, b1, acc[1][1], 0, 0, 0);
      if constexpr (DUALB) {
        short8 c0 = *(const short8*)&Bs2[c * 2048 + (cw + l15) * 32 + quad * 8];
        short8 c1 = *(const short8*)&Bs2[c * 2048 + (cw + 16 + l15) * 32 + quad * 8];
        acc2[0][0] = __builtin_amdgcn_mfma_f32_16x16x32_bf16(a0, c0, acc2[0][0], 0, 0, 0);
        acc2[0][1] = __builtin_amdgcn_mfma_f32_16x16x32_bf16(a0, c1, acc2[0][1], 0, 0, 0);
        acc2[1][0] = __builtin_amdgcn_mfma_f32_16x16x32_bf16(a1, c0, acc2[1][0], 0, 0, 0);
        acc2[1][1] = __builtin_amdgcn_mfma_f32_16x16x32_bf16(a1, c1, acc2[1][1], 0, 0, 0);
      }
    }
  }
#pragma unroll
  for (int mi = 0; mi < 2; ++mi)
#pragma unroll
    for (int nj = 0; nj < 2; ++nj) {
      int colg = n0 + cw + nj * 16 + l15;
      float bv_ = bias ? bias[colg] : 0.f;
      float bv2 = DUALB ? bias[colg + 1024] : 0.f;
      int rbase = r0 + rw + mi * 16 + quad * 4;
      float ov[4];
#pragma unroll
      for (int r = 0; r < 4; ++r) {
        float v = acc[mi][nj][r];
        if constexpr (EPI == 0 || EPI == 5) {
          v += bv_;
        } else if constexpr (EPI == 3) {
          v *= rsp[rbase + r];
        } else if constexpr (EPI == 7) {
          if (zh == 0) v += bv_;   // bias exactly once across K-segments
        } else if constexpr (DUALB) {
          v = gelu_exact(v + bv_) * (acc2[mi][nj][r] + bv2);
        }
        ov[r] = v;
      }
      if constexpr (EPI == 5) {
        if (colg < 512) {
#pragma unroll
          for (int r = 0; r < 4; ++r) sto1(&C[(long)(rbase + r) * ldc + colg], ov[r]);
        } else {
          int bb = rbase >> 11, t0 = rbase & 2047;
          long off = (((long)bb * 4 + ((colg - 512) >> 6)) * 64 + (colg & 63)) * 2048 + t0;
          ushort4 p;
          p.x = f2bu(ov[0]); p.y = f2bu(ov[1]); p.z = f2bu(ov[2]); p.w = f2bu(ov[3]);
          *(ushort4*)((unsigned short*)C2 + off) = p;
        }
      } else if constexpr (EPI == 7) {
#pragma unroll
        for (int r = 0; r < 4; ++r)
          atomicAdd((float*)&C[(long)(rbase + r) * ldc + colg], ov[r]);
      } else if constexpr (EPI == 8) {
        unsigned short* Cu = (unsigned short*)C;
#pragma unroll
        for (int r = 0; r < 4; ++r) {
          float v = ov[r];
          unsigned short hi = f2bu(v);
          unsigned short lo = f2bu(v - b2f(hi));
          long rowo = (long)(rbase + r) * ldc;
          Cu[rowo + colg] = hi;
          Cu[rowo + 1024 + colg] = lo;
          Cu[rowo + 2048 + colg] = hi;
        }
      } else {
#pragma unroll
        for (int r = 0; r < 4; ++r) sto1(&C[(long)(rbase + r) * ldc + colg], ov[r]);
      }
    }
  (void)alpha;
}

// ---------------------------------------------------------------------------
// LayerNorm: one wave per row.  A3 mode writes split-3 bf16 rows (stride 3*DIM).
// ---------------------------------------------------------------------------
template <int DIM, bool RELU, bool ADDPOS, bool DUAL, bool A3, typename OTy>
__global__ __launch_bounds__(256) void ln_kernel(
    const float* __restrict__ in, const float* __restrict__ g,
    const float* __restrict__ b, const float* __restrict__ pos,
    OTy* __restrict__ out0, float* __restrict__ out1)
{
  constexpr int CH = DIM / 64;
  int row = blockIdx.x * 4 + (threadIdx.x >> 6);
  int lane = threadIdx.x & 63;
  const float* rp = in + (long)row * DIM + lane * CH;
  float v[CH];
#pragma unroll
  for (int i = 0; i < CH; ++i) v[i] = rp[i];
  float s = 0.f;
#pragma unroll
  for (int i = 0; i < CH; ++i) s += v[i];
#pragma unroll
  for (int o = 32; o > 0; o >>= 1) s += __shfl_xor(s, o, 64);
  float mean = s * (1.f / DIM);
  float q = 0.f;
#pragma unroll
  for (int i = 0; i < CH; ++i) { float d = v[i] - mean; q += d * d; }
#pragma unroll
  for (int o = 32; o > 0; o >>= 1) q += __shfl_xor(q, o, 64);
  float rstd = rsqrtf(q * (1.f / DIM) + 1e-5f);
  int t = row & 2047;
#pragma unroll
  for (int i = 0; i < CH; ++i) {
    int c = lane * CH + i;
    float o = (v[i] - mean) * rstd * g[c] + b[c];
    if constexpr (ADDPOS) o += pos[(long)t * DIM + c];
    if constexpr (RELU) o = fmaxf(o, 0.f);
    if constexpr (A3) {
      unsigned short hi = f2bu(o);
      unsigned short lo = f2bu(o - b2f(hi));
      unsigned short* op = (unsigned short*)out0 + (long)row * (3 * DIM) + c;
      op[0] = hi; op[DIM] = lo; op[2 * DIM] = hi;
    } else {
      sto1(&out0[(long)row * DIM + c], o);
      if constexpr (DUAL) out1[(long)row * DIM + c] = o;
    }
  }
}

__global__ __launch_bounds__(256) void dinv_kernel(
    const bf16* __restrict__ qf, const float* __restrict__ ksum,
    float* __restrict__ dinv)
{
  int z = blockIdx.x;
  int t = blockIdx.y * 4 + (threadIdx.x >> 6);
  int lane = threadIdx.x & 63;
  const bf16* qr = qf + ((long)z * 2048 + t) * 384;
  const float* ks = ksum + z * 384;
  float acc = 0.f;
#pragma unroll
  for (int i = 0; i < 6; ++i) {
    int j = lane + i * 64;
    acc = fmaf(tof(qr[j]), ks[j], acc);
  }
#pragma unroll
  for (int o = 32; o > 0; o >>= 1) acc += __shfl_xor(acc, o, 64);
  if (lane == 0) dinv[z * 2048 + t] = 1.f / acc;
}

__global__ __launch_bounds__(256) void clf2_kernel(
    const float* __restrict__ c2, const float* __restrict__ w,
    const float* __restrict__ b, float* __restrict__ out)
{
  int row = blockIdx.x * 4 + (threadIdx.x >> 6);
  int lane = threadIdx.x & 63;
  const float* rp = c2 + (long)row * 128 + lane * 2;
  float acc = rp[0] * w[lane * 2] + rp[1] * w[lane * 2 + 1];
#pragma unroll
  for (int o = 32; o > 0; o >>= 1) acc += __shfl_xor(acc, o, 64);
  if (lane == 0) out[row] = acc + b[0];
}

// ---------------------------------------------------------------------------
extern "C" void kernel_launch(void* const* d_in, const int* in_sizes, int n_in,
                              void* d_out, int out_size, void* d_ws, size_t ws_size,
                              hipStream_t stream)
{
  const float* X    = (const float*)d_in[0];
  const float* c0w  = (const float*)d_in[1];
  const float* d1w  = (const float*)d_in[2];
  const float* d1b  = (const float*)d_in[3];
  const float* p1w  = (const float*)d_in[4];
  const float* p1b  = (const float*)d_in[5];
  const float* g1   = (const float*)d_in[6];
  const float* b1   = (const float*)d_in[7];
  const float* m1   = (const float*)d_in[8];
  const float* v1   = (const float*)d_in[9];
  const float* d2w  = (const float*)d_in[10];
  const float* d2b  = (const float*)d_in[11];
  const float* p2w  = (const float*)d_in[12];
  const float* p2b  = (const float*)d_in[13];
  const float* g2   = (const float*)d_in[14];
  const float* b2   = (const float*)d_in[15];
  const float* m2   = (const float*)d_in[16];
  const float* v2   = (const float*)d_in[17];
  const float* projw= (const float*)d_in[18];
  const float* projb= (const float*)d_in[19];
  const float* ln0g = (const float*)d_in[20];
  const float* ln0b = (const float*)d_in[21];
  const float* pos  = (const float*)d_in[22];
  const float* ln1g = (const float*)d_in[23];
  const float* ln1b = (const float*)d_in[24];
  const float* wq   = (const float*)d_in[25];
  const float* bq   = (const float*)d_in[26];
  const float* wk   = (const float*)d_in[27];
  const float* bk   = (const float*)d_in[28];
  const float* wv   = (const float*)d_in[29];
  const float* bv   = (const float*)d_in[30];
  const float* wo   = (const float*)d_in[31];
  const float* bo   = (const float*)d_in[32];
  const float* pmat = (const float*)d_in[33];
  const float* ln2g = (const float*)d_in[34];
  const float* ln2b = (const float*)d_in[35];
  const float* ffw1 = (const float*)d_in[36];
  const float* ffb1 = (const float*)d_in[37];
  const float* ffw2 = (const float*)d_in[38];
  const float* ffb2 = (const float*)d_in[39];
  const float* cw1  = (const float*)d_in[40];
  const float* cb1  = (const float*)d_in[41];
  const float* clng = (const float*)d_in[42];
  const float* clnb = (const float*)d_in[43];
  const float* cw2  = (const float*)d_in[44];
  const float* cb2  = (const float*)d_in[45];
  (void)in_sizes; (void)n_in; (void)out_size; (void)ws_size;

  // ---- workspace (float-slot offsets); within 88.9 MB envelope ----
  float* ws     = (float*)d_ws;
  float* x1     = ws;                          // 1,048,576
  float* x2     = ws + 1048576;                // 1,048,576
  bf16*  lnb16  = (bf16*)(ws + 2097152);       // [4096][256] single (ln1/ln2 out)
  bf16*  hconv3 = (bf16*)(ws + 3670016);       // [4096][768] A3
  // --- arena @5,242,880: A1 during conv; weights+scratch after ---
  bf16*  A1     = (bf16*)(ws + 5242880);       // [4096][64][128], conv only
  bf16*  wqkv1  = (bf16*)(ws + 5242880);       // [4][768][256] single (post-conv)
  float* qkvbias= ws + 6422528;                // [4][768]
  bf16*  f1w1   = (bf16*)(ws + 6425600);       // [4][2048][256] single
  bf16*  f2w1   = (bf16*)(ws + 9571328);       // [4][256][1024] single
  bf16*  wo_bf  = (bf16*)(ws + 11144192);      // [4][256][256]
  bf16*  pm_bf  = (bf16*)(ws + 11275264);      // [4][384][64]
  bf16*  projwT3= (bf16*)(ws + 11324416);      // [256][768]
  bf16*  cw1T3  = (bf16*)(ws + 11422720);      // [128][768]
  bf16*  qkvb   = (bf16*)(ws + 11471872);      // [4096][512] (q,k)
  bf16*  vT     = (bf16*)(ws + 12520448);      // [8][64][2048]
  bf16*  qf     = (bf16*)(ws + 13044736);      // [8][2048][384]
  bf16*  kfT    = (bf16*)(ws + 16190464);      // [8][384][2048]
  bf16*  obufb  = (bf16*)(ws + 19336192);      // [4096][256]
  float* ctx32  = ws + 19860480;               // [8][64][384] fp32
  float* ksum   = ws + 20057088;               // 4096
  float* dinvp  = ws + 20061184;               // 16384
  bf16*  ctxb   = (bf16*)(ws + 20077568);      // [8][64][384] bf16
  float* lnb32  = ws + 20126720;               // [4096][256] (proj out)
  float* c1     = ws + 21175296;               // [4096][128]
  float* c2     = ws + 21699584;               // [4096][128]
  bf16*  gb2    = qkvb;                        // [4096][1024] single (overlay)
  bf16*  sbuf3  = qkvb;                        // [4096][768] A3 (classifier overlay)
  bf16*  pw2_bf = (bf16*)x1;                   // [256][128] pre-conv temp

  const float dn = 0.35355339059327378f;  // 64^-0.25

  // --- conv frontend (pw2_bf staged in x1's slot; x1 written later by ln0) ---
  f2b_kernel<<<128, 256, 0, stream>>>(p2w, pw2_bf, 32768);
  front1_kernel<<<4096, 256, 0, stream>>>(X, c0w, d1w, d1b, p1w, p1b, g1, b1, m1, v1, A1);
  convtail_kernel<<<4096, 256, 0, stream>>>(A1, d2w, d2b, pw2_bf, p2b, g2, b2, m2, v2, hconv3);

  // --- weight conversion (A1 dead; weights live in its span) ---
  pack_qkv1_kernel<<<3072, 256, 0, stream>>>(wq, wk, wv, wqkv1);
  pack_qkvbias_kernel<<<12, 256, 0, stream>>>(bq, bk, bv, qkvbias);
  tconv_kernel<<<dim3(2048, 1, 4), 256, 0, stream>>>(ffw1, f1w1, 256, 2048, 524288, 524288);
  tconv_kernel<<<dim3(1024, 1, 4), 256, 0, stream>>>(ffw2, f2w1, 1024, 256, 262144, 262144);
  tconv_kernel<<<dim3(256, 1, 4), 256, 0, stream>>>(wo, wo_bf, 256, 256, 65536, 65536);
  tconv3_kernel<<<dim3(256, 1, 1), 256, 0, stream>>>(projw, projwT3, 256, 256, 65536, 196608);
  tconv3_kernel<<<dim3(128, 1, 1), 256, 0, stream>>>(cw1, cw1T3, 256, 128, 32768, 98304);
  f2b_kernel<<<384, 256, 0, stream>>>(pmat, pm_bf, 98304);

  // proj (split-3, K=768) + ln0 + pos -> x1 = x2
  mgemm_kernel<float, 0><<<dim3(64, 4, 1), 256, 0, stream>>>(
      hconv3, projwT3, projb, nullptr, nullptr, lnb32, nullptr,
      768, 768, 768, 256, 0, 0, 0, 0, 0, 0, 0, 0, 1, 1.f);
  ln_kernel<256, false, true, true, false, float><<<1024, 256, 0, stream>>>(
      lnb32, ln0g, ln0b, pos, x1, x2);

  for (int l = 0; l < 4; ++l) {
    const bf16* wqkv_l = wqkv1 + (size_t)l * 196608;
    const float* qb_l  = qkvbias + l * 768;
    const bf16* pm_l   = pm_bf + (size_t)l * 24576;
    const bf16* wo_l   = wo_bf + (size_t)l * 65536;
    const float* bov   = bo + l * 256;
    const bf16* f1w_l  = f1w1 + (size_t)l * 524288;
    const float* f1b_l = ffb1 + l * 2048;
    const bf16* f2w_l  = f2w1 + (size_t)l * 262144;
    const float* f2b_l = ffb2 + l * 256;

    // a = LN(x2) -> single bf16
    ln_kernel<256, false, false, false, false, bf16><<<1024, 256, 0, stream>>>(
        x2, ln1g + l * 256, ln1b + l * 256, nullptr, lnb16, nullptr);
    // qkv (single-bf16, K=256)
    mgemm_kernel<bf16, 5><<<dim3(64, 12, 1), 256, 0, stream>>>(
        lnb16, wqkv_l, qb_l, nullptr, nullptr, qkvb, vT,
        256, 256, 256, 512, 0, 0, 0, 0, 0, 0, 0, 0, 1, 1.f);
    // zero ctx32
    zero4_kernel<<<192, 256, 0, stream>>>(ctx32);
    // fused FAVOR: qf (row) + kfT (transposed)
    favor_kernel<<<dim3(32, 6, 16), 256, 0, stream>>>(
        qkvb, pm_l, qf, kfT, dn);
    rowsum_kernel<<<dim3(8, 96), 256, 0, stream>>>(kfT, ksum);
    dinv_kernel<<<dim3(8, 512), 256, 0, stream>>>(qf, ksum, dinvp);
    // ctx split-K: 8 segments of 256 over t
    mgemm_kernel<float, 7><<<dim3(1, 6, 64), 256, 0, stream>>>(
        vT, kfT, nullptr, nullptr, nullptr, ctx32, nullptr,
        256, 2048, 2048, 384, 131072, 256, 786432, 256, 24576, 0, 0, 0, 8, 1.f);
    f2b_kernel<<<768, 256, 0, stream>>>(ctx32, ctxb, 196608);
    // o = (qf @ ctxb^T) * dinv -> obufb
    mgemm_kernel<bf16, 3><<<dim3(32, 1, 8), 256, 0, stream>>>(
        qf, ctxb, nullptr, nullptr, dinvp, obufb, nullptr,
        384, 384, 384, 256, 3145728, 786432, 98304, 24576, 524288, 64, 8192, 2048, 4, 1.f);
    // x1 += o @ wo + bo   (split-K x2, atomic; x1 already holds residual)
    mgemm_kernel<float, 7><<<dim3(64, 4, 2), 256, 0, stream>>>(
        obufb, wo_l, bov, nullptr, nullptr, x1, nullptr,
        128, 256, 256, 256, 0, 128, 0, 128, 0, 0, 0, 0, 2, 1.f);
    // f = LN(x1) -> single bf16
    ln_kernel<256, false, false, false, false, bf16><<<1024, 256, 0, stream>>>(
        x1, ln2g + l * 256, ln2b + l * 256, nullptr, lnb16, nullptr);
    // gb2 = gelu(f@W1a+b1a)*(f@W1b+b1b)  (single-bf16, EPI9, ldc=1024)
    mgemm_kernel<bf16, 9><<<dim3(64, 16, 1), 256, 0, stream>>>(
        lnb16, f1w_l, f1b_l, nullptr, nullptr, gb2, nullptr,
        256, 256, 256, 1024, 0, 0, 0, 0, 0, 0, 262144, 0, 1, 1.f);
    // x2 += gb2 @ ffw2 + b   (single-bf16, K=1024 as 2x512, atomic)
    mgemm_kernel<float, 7><<<dim3(64, 4, 2), 256, 0, stream>>>(
        gb2, f2w_l, f2b_l, nullptr, nullptr, x2, nullptr,
        512, 1024, 1024, 256, 0, 512, 0, 512, 0, 0, 0, 0, 2, 1.f);
  }

  // classifier (split-3 input)
  sumb3_kernel<<<4096, 256, 0, stream>>>(x1, x2, sbuf3);
  mgemm_kernel<float, 0><<<dim3(64, 2, 1), 256, 0, stream>>>(
      sbuf3, cw1T3, cb1, nullptr, nullptr, c1, nullptr,
      768, 768, 768, 128, 0, 0, 0, 0, 0, 0, 0, 0, 1, 1.f);
  ln_kernel<128, true, false, false, false, float><<<1024, 256, 0, stream>>>(
      c1, clng, clnb, nullptr, c2, nullptr);
  clf2_kernel<<<1024, 256, 0, stream>>>(c2, cw2, cb2, (float*)d_out);
}